// Round 5
// baseline (1943.410 us; speedup 1.0000x reference)
//
#include <hip/hip_runtime.h>
#include <hip/hip_bf16.h>

typedef unsigned int u32;
typedef unsigned long long u64;

#define H_FM 100
#define W_FM 150
#define CIN 1024
#define CMID 512
#define NPIX 15000          // H_FM * W_FM
#define NANCH 135000        // NPIX * 9
#define PRE_NMS_N 6000
#define POST_NMS_N 300
#define WPR 94              // ceil(6000/64) words per mask row

typedef __attribute__((ext_vector_type(8))) short short8;
typedef __attribute__((ext_vector_type(8))) __bf16 bf16x8;
typedef __attribute__((ext_vector_type(4))) float f32x4;

__device__ __forceinline__ u32 fkey(float f) {
  u32 u = __float_as_uint(f);
  return (u & 0x80000000u) ? ~u : (u | 0x80000000u);
}

__device__ __forceinline__ u64 shfl64(u64 v, int src) {
  u32 lo = (u32)__shfl((int)(u32)v, src, 64);
  u32 hi = (u32)__shfl((int)(u32)(v >> 32), src, 64);
  return ((u64)hi << 32) | (u64)lo;
}

// MFMA wrapper: tolerate either short8 or bf16x8 builtin operand signature.
struct FragArg {
  short8 v;
  __device__ operator short8() const { return v; }
  __device__ operator bf16x8() const { return __builtin_bit_cast(bf16x8, v); }
};
__device__ __forceinline__ f32x4 mfma16(short8 a, short8 b, f32x4 c) {
  return __builtin_amdgcn_mfma_f32_16x16x32_bf16(FragArg{a}, FragArg{b}, c, 0, 0, 0);
}

#define GLL(gp, lp) __builtin_amdgcn_global_load_lds(                        \
    (const __attribute__((address_space(1))) unsigned int*)(gp),             \
    (__attribute__((address_space(3))) unsigned int*)(lp), 16, 0, 0)

// ---------------------------------------------------------------------------
// bf16x3 split of feature map + zero-page init.
// ---------------------------------------------------------------------------
__device__ __forceinline__ void split3(float f, unsigned short& a,
                                       unsigned short& b, unsigned short& c) {
  __hip_bfloat16 h0 = __float2bfloat16(f);
  float f0 = __bfloat162float(h0);
  float r1 = f - f0;
  __hip_bfloat16 h1 = __float2bfloat16(r1);
  float r2 = r1 - __bfloat162float(h1);
  __hip_bfloat16 h2 = __float2bfloat16(r2);
  a = *(unsigned short*)&h0;
  b = *(unsigned short*)&h1;
  c = *(unsigned short*)&h2;
}

__global__ __launch_bounds__(256) void k_split_fm(
    const float* __restrict__ src, unsigned short* __restrict__ d0,
    unsigned short* __restrict__ d1, unsigned short* __restrict__ d2,
    float* __restrict__ zp)
{
  if (blockIdx.x == 0 && threadIdx.x < 64) zp[threadIdx.x] = 0.f;
  const int n4 = NPIX * CIN / 4;
  for (int i = blockIdx.x * 256 + threadIdx.x; i < n4; i += gridDim.x * 256) {
    float4 v = ((const float4*)src)[i];
    float f[4] = {v.x, v.y, v.z, v.w};
    ushort4 o0, o1, o2;
    unsigned short* p0 = (unsigned short*)&o0;
    unsigned short* p1 = (unsigned short*)&o1;
    unsigned short* p2 = (unsigned short*)&o2;
    #pragma unroll
    for (int e = 0; e < 4; ++e) split3(f[e], p0[e], p1[e], p2[e]);
    ((ushort4*)d0)[i] = o0;
    ((ushort4*)d1)[i] = o1;
    ((ushort4*)d2)[i] = o2;
  }
}

// ---------------------------------------------------------------------------
// Split + transpose weights: W [9216 k][512 n] fp32 -> 3 bf16 planes [512 n][9216 k]
// ---------------------------------------------------------------------------
__global__ __launch_bounds__(256) void k_split_wt(
    const float* __restrict__ Wsrc, unsigned short* __restrict__ t0,
    unsigned short* __restrict__ t1, unsigned short* __restrict__ t2)
{
  __shared__ float tile[64][65];
  const int k0 = blockIdx.x * 64;   // 144 blocks
  const int n0 = blockIdx.y * 64;   // 8 blocks
  const int tid = threadIdx.x;
  const int lr = tid >> 4;
  const int lc = (tid & 15) * 4;
  #pragma unroll
  for (int rr = 0; rr < 64; rr += 16) {
    float4 v = *(const float4*)&Wsrc[(size_t)(k0 + lr + rr) * CMID + n0 + lc];
    tile[lr + rr][lc + 0] = v.x; tile[lr + rr][lc + 1] = v.y;
    tile[lr + rr][lc + 2] = v.z; tile[lr + rr][lc + 3] = v.w;
  }
  __syncthreads();
  const int n = tid >> 2;
  const int kk = (tid & 3) * 16;
  unsigned short b0[16], b1[16], b2[16];
  #pragma unroll
  for (int e = 0; e < 16; ++e) split3(tile[kk + e][n], b0[e], b1[e], b2[e]);
  size_t ob = ((size_t)(n0 + n) * 9216 + k0 + kk) >> 2;
  #pragma unroll
  for (int q = 0; q < 4; ++q) {
    ((ushort4*)t0)[ob + q] = *(ushort4*)&b0[q * 4];
    ((ushort4*)t1)[ob + q] = *(ushort4*)&b1[q * 4];
    ((ushort4*)t2)[ob + q] = *(ushort4*)&b2[q * 4];
  }
}

// ---------------------------------------------------------------------------
// MFMA conv k_conv7: 128m x 64n tile, BK=32, 944 blocks, XOR-swizzled LDS,
// issue->compute->drain pipelining with fragment pre-read into registers.
// LDS: A [split 3][part 8][16 rows x 64B swizzled] = 24576 B
//      B [split 3][part 1][...] at 24576, 12288 B. Total 36864 B.
// ---------------------------------------------------------------------------
__global__ __launch_bounds__(256, 3) void k_conv7(
    const unsigned short* __restrict__ fm0, const unsigned short* __restrict__ fm1,
    const unsigned short* __restrict__ fm2, const unsigned short* __restrict__ wt0,
    const unsigned short* __restrict__ wt1, const unsigned short* __restrict__ wt2,
    const float* __restrict__ br, const float* __restrict__ zp,
    float* __restrict__ rpn)
{
  __shared__ char lds[36864];
  const int tid = threadIdx.x;
  const int ll = tid & 63;
  const int w = tid >> 6;
  const int bn = (blockIdx.x & 7) * 64;
  const int bm = (blockIdx.x >> 3) * 128;
  const int wm = (w >> 1) * 64;
  const int wn = (w & 1) * 32;

  // staging lane geometry: lane L covers (row lp, stored-quad L&3) of a 16-row part
  const int lp = ll >> 2;
  const u32 sqb = (u32)((ll & 3) ^ ((ll >> 3) & 3)) * 16u;  // swizzled source quad

  // A staging rows: parts w and w+4
  const int pm0 = bm + w * 16 + lp;
  const int pm1 = bm + (w + 4) * 16 + lp;
  const int y0 = pm0 / W_FM, x0 = pm0 - y0 * W_FM;
  const int y1 = pm1 / W_FM, x1 = pm1 - y1 * W_FM;
  const bool mv0 = pm0 < NPIX, mv1 = pm1 < NPIX;

  // B staging row: part w
  const u32 boff = (u32)(bn + w * 16 + lp) * 18432u + sqb;

  // fragment-read LDS addresses (swizzle term is lane-only: see derivation)
  const int fr = ll & 15;
  const u32 fswzb = (u32)((ll >> 4) ^ ((fr >> 1) & 3)) * 16u;
  const u32 aAddr = (u32)(wm + fr) * 64u + fswzb;
  const u32 bAddr = 24576u + (u32)(wn + fr) * 64u + fswzb;

  const char* fmB[3] = {(const char*)fm0, (const char*)fm1, (const char*)fm2};
  const char* wtB[3] = {(const char*)wt0, (const char*)wt1, (const char*)wt2};
  const char* zpb = (const char*)zp + sqb;

  u32 aofs0 = 0, aofs1 = 0;
  bool av0 = false, av1 = false;

  auto segSetup = [&](int seg) {
    int dy = seg / 3 - 1, dx = seg - (seg / 3) * 3 - 1;
    int sy0 = y0 + dy, sx0 = x0 + dx;
    int sy1 = y1 + dy, sx1 = x1 + dx;
    av0 = mv0 && (unsigned)sy0 < H_FM && (unsigned)sx0 < W_FM;
    av1 = mv1 && (unsigned)sy1 < H_FM && (unsigned)sx1 < W_FM;
    aofs0 = (u32)(sy0 * W_FM + sx0) * 2048u + sqb;
    aofs1 = (u32)(sy1 * W_FM + sx1) * 2048u + sqb;
  };

  auto stage = [&](int seg, u32 chb) {
    #pragma unroll
    for (int s = 0; s < 3; ++s) {
      const char* g0 = av0 ? (fmB[s] + aofs0 + chb) : zpb;
      const char* g1 = av1 ? (fmB[s] + aofs1 + chb) : zpb;
      GLL(g0, lds + s * 8192 + w * 1024);
      GLL(g1, lds + s * 8192 + (w + 4) * 1024);
    }
    const u32 ko = (u32)seg * 2048u + chb;
    #pragma unroll
    for (int s = 0; s < 3; ++s)
      GLL(wtB[s] + (boff + ko), lds + 24576 + s * 4096 + w * 1024);
  };

  short8 Af[3][4], Bf[3][2];
  auto readFrags = [&]() {
    #pragma unroll
    for (int s = 0; s < 3; ++s) {
      #pragma unroll
      for (int i = 0; i < 4; ++i)
        Af[s][i] = *(const short8*)(lds + aAddr + s * 8192 + i * 1024);
      #pragma unroll
      for (int j = 0; j < 2; ++j)
        Bf[s][j] = *(const short8*)(lds + bAddr + s * 4096 + j * 1024);
    }
  };

  f32x4 acc[4][2];
  #pragma unroll
  for (int i = 0; i < 4; ++i)
    #pragma unroll
    for (int j = 0; j < 2; ++j) acc[i][j] = (f32x4){0.f, 0.f, 0.f, 0.f};

  segSetup(0);
  stage(0, 0);
  __syncthreads();
  readFrags();

  for (int it = 0; it < 288; ++it) {
    const int nit = it + 1;
    const bool more = nit < 288;
    if (more && (nit & 31) == 0) segSetup(nit >> 5);
    __syncthreads();                    // all waves done reading chunk `it`
    if (more) stage(nit >> 5, (u32)(nit & 31) * 64u);
    #pragma unroll
    for (int i = 0; i < 4; ++i)
      #pragma unroll
      for (int j = 0; j < 2; ++j) {
        f32x4 c = acc[i][j];
        c = mfma16(Af[0][i], Bf[0][j], c);
        c = mfma16(Af[0][i], Bf[1][j], c);
        c = mfma16(Af[1][i], Bf[0][j], c);
        c = mfma16(Af[1][i], Bf[1][j], c);
        c = mfma16(Af[0][i], Bf[2][j], c);
        c = mfma16(Af[2][i], Bf[0][j], c);
        acc[i][j] = c;
      }
    __syncthreads();                    // staged chunk landed (drain overlapped)
    if (more) readFrags();
  }

  // epilogue: bias + relu + store (C/D: row=(lane>>4)*4+reg, col=lane&15)
  #pragma unroll
  for (int i = 0; i < 4; ++i) {
    const int mb = bm + wm + i * 16 + ((ll >> 4) << 2);
    #pragma unroll
    for (int r = 0; r < 4; ++r) {
      const int m = mb + r;
      if (m < NPIX) {
        float* op = rpn + (size_t)m * CMID;
        #pragma unroll
        for (int j = 0; j < 2; ++j) {
          const int n = bn + wn + j * 16 + (ll & 15);
          op[n] = fmaxf(acc[i][j][r] + br[n], 0.f);
        }
      }
    }
  }
}

// ---------------------------------------------------------------------------
// Pack head weights: Wp[512][64] (cls 0-17, bbox 18-53, pad), bp[64].
// ---------------------------------------------------------------------------
__global__ __launch_bounds__(256) void k_packW(
    const float* __restrict__ Ws, const float* __restrict__ bs,
    const float* __restrict__ Wb, const float* __restrict__ bb,
    float* __restrict__ Wp, float* __restrict__ bp)
{
  int tt = blockIdx.x * 256 + threadIdx.x;    // 128 blocks -> 32768
  int k = tt >> 6, o = tt & 63;
  float v = (o < 18) ? Ws[k * 18 + o] : ((o < 54) ? Wb[k * 36 + (o - 18)] : 0.f);
  Wp[tt] = v;
  if (tt < 64) bp[tt] = (tt < 18) ? bs[tt] : ((tt < 54) ? bb[tt - 18] : 0.f);
}

// ---------------------------------------------------------------------------
// Head GEMM: vals[M=15000][64] = rpn[M][512] * Wp[512][64] + bp.
// ---------------------------------------------------------------------------
__global__ __launch_bounds__(256) void k_headgemm(
    const float* __restrict__ rpn, const float* __restrict__ Wp,
    const float* __restrict__ bp, float* __restrict__ vals)
{
  __shared__ float As[32][132];
  __shared__ float Bs[32][64];
  const int tid = threadIdx.x;
  const int bm = blockIdx.x * 128;
  const int mt = tid >> 3;
  const int nt = tid & 7;
  const int kg = tid & 7;
  const int ar = tid >> 3;
  const int n4 = (tid & 15) * 4;
  const int kr = tid >> 4;
  const float4 z4 = make_float4(0.f, 0.f, 0.f, 0.f);

  float acc[4][8];
  #pragma unroll
  for (int i = 0; i < 4; ++i)
    #pragma unroll
    for (int j = 0; j < 8; ++j) acc[i][j] = 0.f;

  for (int kc = 0; kc < 512; kc += 32) {
    __syncthreads();
    #pragma unroll
    for (int rr = 0; rr < 128; rr += 32) {
      int m = bm + ar + rr;
      float4 v = (m < NPIX) ? *(const float4*)&rpn[(size_t)m * CMID + kc + kg * 4] : z4;
      As[kg * 4 + 0][ar + rr] = v.x; As[kg * 4 + 1][ar + rr] = v.y;
      As[kg * 4 + 2][ar + rr] = v.z; As[kg * 4 + 3][ar + rr] = v.w;
    }
    *(float4*)&Bs[kr][n4]      = *(const float4*)&Wp[(kc + kr) * 64 + n4];
    *(float4*)&Bs[kr + 16][n4] = *(const float4*)&Wp[(kc + kr + 16) * 64 + n4];
    __syncthreads();
    #pragma unroll
    for (int kk = 0; kk < 32; ++kk) {
      float4 a = *(const float4*)&As[kk][mt * 4];
      float4 b0 = *(const float4*)&Bs[kk][nt * 8];
      float4 b1 = *(const float4*)&Bs[kk][nt * 8 + 4];
      float av[4] = {a.x, a.y, a.z, a.w};
      float bv[8] = {b0.x, b0.y, b0.z, b0.w, b1.x, b1.y, b1.z, b1.w};
      #pragma unroll
      for (int i = 0; i < 4; ++i)
        #pragma unroll
        for (int j = 0; j < 8; ++j) acc[i][j] = fmaf(av[i], bv[j], acc[i][j]);
    }
  }
  float bias[8];
  #pragma unroll
  for (int j = 0; j < 8; ++j) bias[j] = bp[nt * 8 + j];
  #pragma unroll
  for (int r = 0; r < 4; ++r) {
    int m = bm + mt * 4 + r;
    if (m < NPIX) {
      float o[8];
      #pragma unroll
      for (int j = 0; j < 8; ++j) o[j] = acc[r][j] + bias[j];
      float* op = vals + (size_t)m * 64 + nt * 8;
      *(float4*)op = *(float4*)&o[0];
      *(float4*)(op + 4) = *(float4*)&o[4];
    }
  }
}

// ---------------------------------------------------------------------------
// Decode: softmax + anchor decode + clip + min-size filter. 1 thread/anchor.
// ---------------------------------------------------------------------------
__global__ __launch_bounds__(256) void k_decode(
    const float* __restrict__ vals, const int* __restrict__ img,
    float* __restrict__ fg, float4* __restrict__ boxes)
{
  int gi = blockIdx.x * 256 + threadIdx.x;
  if (gi >= NANCH) return;
  const int p = gi / 9, a = gi - p * 9;
  const float AW[9] = {184.f, 368.f, 736.f, 128.f, 256.f, 512.f,  88.f, 176.f, 352.f};
  const float AH[9] = { 96.f, 192.f, 384.f, 128.f, 256.f, 512.f, 176.f, 352.f, 704.f};
  const int y = p / W_FM, x = p - y * W_FM;
  const float* row = vals + (size_t)p * 64;

  float c0 = row[2 * a], c1 = row[2 * a + 1];
  float score = 1.f / (1.f + expf(c0 - c1));

  float dxv = row[18 + 4 * a + 0];
  float dyv = row[18 + 4 * a + 1];
  float dwv = row[18 + 4 * a + 2];
  float dhv = row[18 + 4 * a + 3];

  float aw = AW[a], ah = AH[a];
  float acx = (float)(x * 16 + 8);
  float acy = (float)(y * 16 + 8);
  float pcx = dxv * aw + acx;
  float pcy = dyv * ah + acy;
  float pw = expf(dwv) * aw;
  float ph = expf(dhv) * ah;

  float imh1 = (float)img[0] - 1.f;
  float imw1 = (float)img[1] - 1.f;
  float b0 = fminf(fmaxf(pcx - 0.5f * pw, 0.f), imw1);
  float b1 = fminf(fmaxf(pcy - 0.5f * ph, 0.f), imh1);
  float b2 = fminf(fmaxf(pcx + 0.5f * pw, 0.f), imw1);
  float b3 = fminf(fmaxf(pcy + 0.5f * ph, 0.f), imh1);

  float bw = b2 - b0 + 1.f, bh = b3 - b1 + 1.f;
  if (!(bw >= 16.f && bh >= 16.f)) score = -1e9f;

  fg[gi] = score;
  boxes[gi] = make_float4(b0, b1, b2, b3);
}

// ---------------------------------------------------------------------------
// Radix-select (exact top-6000 threshold) machinery.
// ctl[0]=prefix/threshold, ctl[1]=kneed, ctl[2]=cntA, ctl[3]=cntB
// ---------------------------------------------------------------------------
__global__ void k_init(u32* __restrict__ hist, u32* __restrict__ ctl) {
  hist[threadIdx.x] = 0;
  if (threadIdx.x == 0) { ctl[0] = 0; ctl[1] = PRE_NMS_N; ctl[2] = 0; ctl[3] = 0; }
}

__global__ __launch_bounds__(256) void k_hist(
    const float* __restrict__ fg, u32* __restrict__ hist,
    const u32* __restrict__ ctl, int pass)
{
  __shared__ u32 h[256];
  h[threadIdx.x] = 0;
  __syncthreads();
  const int shift = 24 - 8 * pass;
  const u32 prefix = ctl[0];
  for (int i = blockIdx.x * 256 + threadIdx.x; i < NANCH; i += 128 * 256) {
    u32 key = fkey(fg[i]);
    bool match = (pass == 0) || ((key >> (shift + 8)) == prefix);
    if (match) atomicAdd(&h[(key >> shift) & 255], 1u);
  }
  __syncthreads();
  u32 c = h[threadIdx.x];
  if (c) atomicAdd(&hist[threadIdx.x], c);
}

__global__ void k_scan(u32* __restrict__ hist, u32* __restrict__ ctl) {
  if (threadIdx.x == 0) {
    u32 kneed = ctl[1];
    u32 cum = 0;
    int d = 0;
    for (int dd = 255; dd >= 0; --dd) {
      u32 c = hist[dd];
      if (cum + c >= kneed) { d = dd; break; }
      cum += c;
    }
    ctl[0] = (ctl[0] << 8) | (u32)d;
    ctl[1] = kneed - cum;
  }
  __syncthreads();
  hist[threadIdx.x] = 0;
}

__global__ __launch_bounds__(256) void k_compact(
    const float* __restrict__ fg, u32* __restrict__ ctl,
    u64* __restrict__ listA, u32* __restrict__ listB)
{
  int i = blockIdx.x * 256 + threadIdx.x;
  if (i >= NANCH) return;
  u32 T = ctl[0];
  u32 key = fkey(fg[i]);
  if (key > T) {
    u32 slot = atomicAdd(&ctl[2], 1u);
    listA[slot] = ((u64)key << 32) | (u64)(0xFFFFFFFFu - (u32)i);
  } else if (key == T) {
    u32 slot = atomicAdd(&ctl[3], 1u);
    if (slot < 8192) listB[slot] = (u32)i;
  }
}

__global__ __launch_bounds__(256) void k_tiefix(
    u32* __restrict__ ctl, const u32* __restrict__ listB, u64* __restrict__ listA)
{
  __shared__ u32 s[8192];
  const int tid = threadIdx.x;
  const u32 kneed = ctl[1];
  const u32 base = ctl[2];
  const u32 cntB = min(ctl[3], 8192u);
  const u32 T = ctl[0];
  if (kneed == 0) return;
  if (cntB == kneed) {
    for (u32 t = tid; t < kneed; t += 256)
      listA[base + t] = ((u64)T << 32) | (u64)(0xFFFFFFFFu - listB[t]);
    return;
  }
  u32 n2 = 1;
  while (n2 < cntB) n2 <<= 1;
  for (u32 i = tid; i < n2; i += 256) s[i] = (i < cntB) ? listB[i] : 0xFFFFFFFFu;
  __syncthreads();
  for (u32 k = 2; k <= n2; k <<= 1) {
    for (u32 j = k >> 1; j > 0; j >>= 1) {
      for (u32 i = tid; i < n2; i += 256) {
        u32 ixj = i ^ j;
        if (ixj > i) {
          u32 a = s[i], b = s[ixj];
          bool up = ((i & k) == 0);
          if ((a > b) == up) { s[i] = b; s[ixj] = a; }
        }
      }
      __syncthreads();
    }
  }
  for (u32 t = tid; t < kneed; t += 256)
    listA[base + t] = ((u64)T << 32) | (u64)(0xFFFFFFFFu - s[t]);
}

__global__ __launch_bounds__(1024) void k_sort(
    const u64* __restrict__ listA, u64* __restrict__ sorted)
{
  __shared__ u64 s[8192];
  const int tid = threadIdx.x;
  for (int i = tid; i < 8192; i += 1024) s[i] = (i < PRE_NMS_N) ? listA[i] : 0ull;
  __syncthreads();
  for (int k = 2; k <= 8192; k <<= 1) {
    for (int j = k >> 1; j > 0; j >>= 1) {
      for (int i = tid; i < 8192; i += 1024) {
        int ixj = i ^ j;
        if (ixj > i) {
          u64 a = s[i], b = s[ixj];
          bool up = ((i & k) == 0);
          if ((a < b) == up) { s[i] = b; s[ixj] = a; }
        }
      }
      __syncthreads();
    }
  }
  for (int i = tid; i < 8192; i += 1024) sorted[i] = s[i];
}

__global__ __launch_bounds__(256) void k_gather(
    const u64* __restrict__ sorted, const float4* __restrict__ boxes,
    float4* __restrict__ tb)
{
  int t = blockIdx.x * 256 + threadIdx.x;
  if (t >= PRE_NMS_N) return;
  u64 p = sorted[t];
  u32 idx = 0xFFFFFFFFu - (u32)(p & 0xFFFFFFFFull);
  tb[t] = boxes[idx];
}

// ---------------------------------------------------------------------------
// Suppression bitmask: mask[i][w] bit b == (IoU(i, w*64+b) > 0.7 && j > i)
// ---------------------------------------------------------------------------
__global__ __launch_bounds__(64) void k_mask(
    const float4* __restrict__ tb, u64* __restrict__ mask)
{
  __shared__ float4 cb[64];
  const int bj = blockIdx.x, bi = blockIdx.y, t = threadIdx.x;
  const int j0 = bj * 64;
  const int jn = min(64, PRE_NMS_N - j0);
  if (t < jn) cb[t] = tb[j0 + t];
  __syncthreads();
  const int i = bi * 64 + t;
  if (i >= PRE_NMS_N) return;
  const float4 b = tb[i];
  const float ai = (b.z - b.x + 1.f) * (b.w - b.y + 1.f);
  u64 bits = 0;
  for (int tt = 0; tt < jn; ++tt) {
    int j = j0 + tt;
    if (j <= i) continue;
    float4 c = cb[tt];
    float iw = fminf(b.z, c.z) - fmaxf(b.x, c.x) + 1.f;
    float ih = fminf(b.w, c.w) - fmaxf(b.y, c.y) + 1.f;
    float inter = fmaxf(iw, 0.f) * fmaxf(ih, 0.f);
    float aj = (c.z - c.x + 1.f) * (c.w - c.y + 1.f);
    float iou = inter / (ai + aj - inter);
    if (iou > 0.7f) bits |= (1ull << tt);
  }
  mask[(size_t)i * WPR + bj] = bits;
}

// ---------------------------------------------------------------------------
// Single-wave greedy NMS walk with register-resident removed-bitmask;
// early exit after 300 kept (only the first 300 kept reach the output).
// ---------------------------------------------------------------------------
__global__ __launch_bounds__(64) void k_nms(
    const u64* __restrict__ mask, const float* __restrict__ tb,
    const u64* __restrict__ sorted, float* __restrict__ out)
{
  const int lane = threadIdx.x;
  u64 r0 = 0, r1 = 0;   // removed words: lane -> word lane; lane -> word 64+lane
  int kept = 0;
  const u32 kcut = fkey(-1e8f);
  for (int i = 0; i < PRE_NMS_N; ++i) {
    const int w = i >> 6, b = i & 63;
    u64 v0 = shfl64(r0, w & 63);
    u64 v1 = shfl64(r1, w & 63);
    u64 word = (w < 64) ? v0 : v1;
    if (!((word >> b) & 1ull)) {
      u32 key = (u32)(sorted[i] >> 32);
      if (key <= kcut) break;          // sorted tail: all filtered -> zeros
      if (lane < 4) out[kept * 4 + lane] = tb[i * 4 + lane];
      ++kept;
      if (kept >= POST_NMS_N) break;
      const u64* row = mask + (size_t)i * WPR;
      r0 |= row[lane];
      if (lane < WPR - 64) r1 |= row[64 + lane];
    }
  }
  for (int j = kept * 4 + lane; j < POST_NMS_N * 4; j += 64) out[j] = 0.f;
}

// ---------------------------------------------------------------------------
extern "C" void kernel_launch(void* const* d_in, const int* in_sizes, int n_in,
                              void* d_out, int out_size, void* d_ws, size_t ws_size,
                              hipStream_t stream) {
  const float* fm  = (const float*)d_in[0];
  const float* Wr  = (const float*)d_in[1];
  const float* br  = (const float*)d_in[2];
  const float* Wsc = (const float*)d_in[3];
  const float* bsc = (const float*)d_in[4];
  const float* Wbb = (const float*)d_in[5];
  const float* bbb = (const float*)d_in[6];
  const int*   img = (const int*)d_in[7];
  float* out = (float*)d_out;

  char* w = (char*)d_ws;
  size_t off = 0;
  auto alloc = [&](size_t bytes) {
    size_t p = off;
    off = (off + bytes + 255) & ~(size_t)255;
    return p;
  };
  float* rpn    = (float*)(w + alloc((size_t)NPIX * CMID * 4));       // 30.72 MB
  float* fg     = (float*)(w + alloc((size_t)NANCH * 4));
  float4* boxes = (float4*)(w + alloc((size_t)NANCH * 16));
  u32* hist     = (u32*)(w + alloc(1024));
  u32* ctl      = (u32*)(w + alloc(64));
  u64* listA    = (u64*)(w + alloc((size_t)PRE_NMS_N * 8));
  u32* listB    = (u32*)(w + alloc(8192 * 4));
  u64* sorted   = (u64*)(w + alloc(8192 * 8));
  float4* topbox= (float4*)(w + alloc((size_t)PRE_NMS_N * 16));
  u64* mask     = (u64*)(w + alloc((size_t)PRE_NMS_N * WPR * 8));     // 4.5 MB
  float* zp     = (float*)(w + alloc(256));
  float* Wp     = (float*)(w + alloc(512 * 64 * 4));
  float* bp     = (float*)(w + alloc(64 * 4));
  float* vals   = (float*)(w + alloc((size_t)NPIX * 64 * 4));         // 3.84 MB
  size_t fb = (size_t)NPIX * CIN * 2;
  size_t wb = (size_t)9216 * CMID * 2;
  unsigned short* fm0 = (unsigned short*)(w + alloc(fb));
  unsigned short* fm1 = (unsigned short*)(w + alloc(fb));
  unsigned short* fm2 = (unsigned short*)(w + alloc(fb));
  unsigned short* wt0 = (unsigned short*)(w + alloc(wb));
  unsigned short* wt1 = (unsigned short*)(w + alloc(wb));
  unsigned short* wt2 = (unsigned short*)(w + alloc(wb));

  // 1. precision-split + transpose + pack
  k_split_fm<<<dim3(1024), dim3(256), 0, stream>>>(fm, fm0, fm1, fm2, zp);
  k_split_wt<<<dim3(144, 8), dim3(256), 0, stream>>>(Wr, wt0, wt1, wt2);
  k_packW<<<dim3(128), dim3(256), 0, stream>>>(Wsc, bsc, Wbb, bbb, Wp, bp);
  // 2. conv (3x3 + bias + relu), swizzled-LDS pipelined MFMA
  k_conv7<<<dim3(118 * 8), dim3(256), 0, stream>>>(
      fm0, fm1, fm2, wt0, wt1, wt2, br, zp, rpn);
  // 3. heads + decode
  k_headgemm<<<dim3(118), dim3(256), 0, stream>>>(rpn, Wp, bp, vals);
  k_decode<<<dim3((NANCH + 255) / 256), dim3(256), 0, stream>>>(vals, img, fg, boxes);
  // 4. exact top-6000 radix select
  k_init<<<1, 256, 0, stream>>>(hist, ctl);
  for (int pass = 0; pass < 4; ++pass) {
    k_hist<<<128, 256, 0, stream>>>(fg, hist, ctl, pass);
    k_scan<<<1, 256, 0, stream>>>(hist, ctl);
  }
  k_compact<<<(NANCH + 255) / 256, 256, 0, stream>>>(fg, ctl, listA, listB);
  k_tiefix<<<1, 256, 0, stream>>>(ctl, listB, listA);
  // 5. sort (desc score, asc index) + gather
  k_sort<<<1, 1024, 0, stream>>>(listA, sorted);
  k_gather<<<(PRE_NMS_N + 255) / 256, 256, 0, stream>>>(sorted, boxes, topbox);
  // 6. NMS mask + single-wave walk + emit 300
  k_mask<<<dim3(WPR, WPR), 64, 0, stream>>>(topbox, mask);
  k_nms<<<1, 64, 0, stream>>>(mask, (const float*)topbox, sorted, out);
}

// Round 6
// 1238.413 us; speedup vs baseline: 1.5693x; 1.5693x over previous
//
#include <hip/hip_runtime.h>
#include <hip/hip_bf16.h>

typedef unsigned int u32;
typedef unsigned long long u64;

#define H_FM 100
#define W_FM 150
#define CIN 1024
#define CMID 512
#define NPIX 15000          // H_FM * W_FM
#define NANCH 135000        // NPIX * 9
#define PRE_NMS_N 6000
#define POST_NMS_N 300
#define WPR 94              // ceil(6000/64) words per mask row

// padded A-pack geometry: rows -1..102 (104), cols -1..150 (152)
#define PW 152
#define PH 104
#define PPIX (PW * PH)          // 15808 pixels
#define CHSZ ((u64)PPIX * 64)   // bytes per (chunk) plane = 1,011,712
#define ASPLIT (32 * CHSZ)      // per split = 32,374,784
#define BSPLIT ((u64)9216 * 512 * 2)  // 9,437,184 per split

typedef __attribute__((ext_vector_type(8))) short short8;
typedef __attribute__((ext_vector_type(8))) __bf16 bf16x8;
typedef __attribute__((ext_vector_type(4))) float f32x4;

__device__ __forceinline__ u32 fkey(float f) {
  u32 u = __float_as_uint(f);
  return (u & 0x80000000u) ? ~u : (u | 0x80000000u);
}

__device__ __forceinline__ u64 shfl64(u64 v, int src) {
  u32 lo = (u32)__shfl((int)(u32)v, src, 64);
  u32 hi = (u32)__shfl((int)(u32)(v >> 32), src, 64);
  return ((u64)hi << 32) | (u64)lo;
}

// MFMA wrapper: tolerate either short8 or bf16x8 builtin operand signature.
struct FragArg {
  short8 v;
  __device__ operator short8() const { return v; }
  __device__ operator bf16x8() const { return __builtin_bit_cast(bf16x8, v); }
};
__device__ __forceinline__ f32x4 mfma16(short8 a, short8 b, f32x4 c) {
  return __builtin_amdgcn_mfma_f32_16x16x32_bf16(FragArg{a}, FragArg{b}, c, 0, 0, 0);
}

#define GLL(gp, lp) __builtin_amdgcn_global_load_lds(                        \
    (const __attribute__((address_space(1))) unsigned int*)(gp),             \
    (__attribute__((address_space(3))) unsigned int*)(lp), 16, 0, 0)

__device__ __forceinline__ void split3(float f, unsigned short& a,
                                       unsigned short& b, unsigned short& c) {
  __hip_bfloat16 h0 = __float2bfloat16(f);
  float f0 = __bfloat162float(h0);
  float r1 = f - f0;
  __hip_bfloat16 h1 = __float2bfloat16(r1);
  float r2 = r1 - __bfloat162float(h1);
  __hip_bfloat16 h2 = __float2bfloat16(r2);
  a = *(unsigned short*)&h0;
  b = *(unsigned short*)&h1;
  c = *(unsigned short*)&h2;
}

// ---------------------------------------------------------------------------
// Zero the halo of the packed A planes (808 halo pixels per chunk-plane).
// ids: 3 splits x 32 chunks x 808 = 77568, one 64-B pixel-chunk each.
// ---------------------------------------------------------------------------
__global__ __launch_bounds__(256) void k_zeroA(unsigned short* __restrict__ Ap)
{
  int id = blockIdx.x * 256 + threadIdx.x;
  if (id >= 3 * 32 * 808) return;
  int sc = id / 808, h = id - sc * 808;
  int s = sc >> 5, c = sc & 31;
  int pp;
  if (h < 152) pp = h;                                    // row 0
  else if (h < 608) pp = 101 * 152 + (h - 152);           // rows 101..103
  else { int k = h - 608; pp = ((k >> 1) + 1) * 152 + ((k & 1) ? 151 : 0); }
  float4* dst = (float4*)((char*)Ap + (u64)s * ASPLIT + (u64)c * CHSZ + (u64)pp * 64);
  float4 z = make_float4(0.f, 0.f, 0.f, 0.f);
  dst[0] = z; dst[1] = z; dst[2] = z; dst[3] = z;
}

// ---------------------------------------------------------------------------
// Split fm into 3 bf16 planes, packed [split][chunk32][padded pixel][64 B].
// ---------------------------------------------------------------------------
__global__ __launch_bounds__(256) void k_splitA(
    const float* __restrict__ src, unsigned short* __restrict__ Ap)
{
  const int ntot = NPIX * 256;      // (pixel, group-of-4-ch)
  for (int id = blockIdx.x * 256 + threadIdx.x; id < ntot; id += gridDim.x * 256) {
    int p = id >> 8, g = id & 255;
    float4 v = *(const float4*)(src + (size_t)p * 1024 + g * 4);
    float f[4] = {v.x, v.y, v.z, v.w};
    ushort4 o0, o1, o2;
    unsigned short* q0 = (unsigned short*)&o0;
    unsigned short* q1 = (unsigned short*)&o1;
    unsigned short* q2 = (unsigned short*)&o2;
    #pragma unroll
    for (int e = 0; e < 4; ++e) split3(f[e], q0[e], q1[e], q2[e]);
    int yy = p / 150;
    int pp = (yy + 1) * 152 + (p - yy * 150) + 1;
    u64 off = (u64)(g >> 3) * CHSZ + (u64)pp * 64 + (g & 7) * 8;
    *(ushort4*)((char*)Ap + off) = o0;
    *(ushort4*)((char*)Ap + ASPLIT + off) = o1;
    *(ushort4*)((char*)Ap + 2 * ASPLIT + off) = o2;
  }
}

// ---------------------------------------------------------------------------
// Split + transpose + pack weights: W [9216 k][512 n] fp32 ->
// 3 bf16 planes [nblk 4][seg 9][chunk 32][row 128][64 B].
// ---------------------------------------------------------------------------
__global__ __launch_bounds__(256) void k_splitB(
    const float* __restrict__ Wsrc, unsigned short* __restrict__ Bp)
{
  __shared__ float tile[64][65];
  const int k0 = blockIdx.x * 64;   // 144 blocks
  const int n0 = blockIdx.y * 64;   // 8 blocks
  const int tid = threadIdx.x;
  const int lr = tid >> 4;
  const int lc = (tid & 15) * 4;
  #pragma unroll
  for (int rr = 0; rr < 64; rr += 16) {
    float4 v = *(const float4*)&Wsrc[(size_t)(k0 + lr + rr) * CMID + n0 + lc];
    tile[lr + rr][lc + 0] = v.x; tile[lr + rr][lc + 1] = v.y;
    tile[lr + rr][lc + 2] = v.z; tile[lr + rr][lc + 3] = v.w;
  }
  __syncthreads();
  const int n = n0 + (tid >> 2);
  const int kk = k0 + (tid & 3) * 16;
  unsigned short b0[16], b1[16], b2[16];
  #pragma unroll
  for (int e = 0; e < 16; ++e)
    split3(tile[(tid & 3) * 16 + e][tid >> 2], b0[e], b1[e], b2[e]);
  const int nblk = n >> 7, row = n & 127;
  const int seg = kk >> 10, chunk = (kk >> 5) & 31, ch = kk & 31;
  u64 base = ((u64)((nblk * 9 + seg) * 32 + chunk)) * 8192 + row * 64 + ch * 2;
  #pragma unroll
  for (int q = 0; q < 4; ++q) {
    *(ushort4*)((char*)Bp + base + q * 8) = *(ushort4*)&b0[q * 4];
    *(ushort4*)((char*)Bp + BSPLIT + base + q * 8) = *(ushort4*)&b1[q * 4];
    *(ushort4*)((char*)Bp + 2 * BSPLIT + base + q * 8) = *(ushort4*)&b2[q * 4];
  }
}

// ---------------------------------------------------------------------------
// k_conv8: 128x128 tile, 472 blocks, BK=32, bf16x3 (6 products).
// XOR-swizzled LDS (conflict-free), register frag pre-read, single-buffer
// stage(next)->compute->drain pipeline, dense ~1KB GLL sources from packed
// A/B layouts, zero-halo padding (no validity masks).
// LDS: A [s3][part8][row16][64B] = 24 KB; B same at +24576. Total 48 KB.
// ---------------------------------------------------------------------------
__global__ __launch_bounds__(256, 2) void k_conv8(
    const unsigned short* __restrict__ Ap, const unsigned short* __restrict__ Bp,
    const float* __restrict__ br, float* __restrict__ rpn)
{
  __shared__ char lds[49152];
  const int tid = threadIdx.x;
  const int L = tid & 63;
  const int w = tid >> 6;
  const int nblk = blockIdx.x & 3;
  const int bn = nblk * 128;
  const int bm = (blockIdx.x >> 2) * 128;
  const int wm = (w >> 1) * 64, wn = (w & 1) * 64;

  // staging lane geometry: row r = L>>2, LDS slot quad sq = L&3,
  // source data-quad dq = sq ^ ((r>>1)&3)  (XOR swizzle)
  const int r = L >> 2;
  const u32 dqb = (u32)(((L & 3) ^ ((r >> 1) & 3)) * 16);

  // A pixel coords for parts w and w+4
  int ay[2], ax[2];
  {
    int m0 = bm + w * 16 + r;       ay[0] = m0 / 150; ax[0] = m0 - ay[0] * 150;
    int m1 = bm + (w + 4) * 16 + r; ay[1] = m1 / 150; ax[1] = m1 - ay[1] * 150;
  }
  // B source row offsets (within a (nblk,seg,chunk) 8-KB slab)
  const u32 brow0 = (u32)((w * 16 + r) * 64) + dqb;
  const u32 brow1 = (u32)(((w + 4) * 16 + r) * 64) + dqb;
  const u64 bbase = (u64)nblk * 9 * 32 * 8192;

  // fragment-read addresses (swizzle-matched)
  const int fr = L & 15, fq = L >> 4;
  const u32 fsw = (u32)((fq ^ ((fr >> 1) & 3)) * 16);
  const u32 aF = (u32)((wm >> 4) * 1024 + fr * 64) + fsw;        // + s*8192 + i*1024
  const u32 bF = 24576u + (u32)((wn >> 4) * 1024 + fr * 64) + fsw;

  u32 apix[2];
  auto segSetup = [&](int seg) {
    int dy = seg / 3 - 1, dx = seg - (seg / 3) * 3 - 1;
    apix[0] = (u32)(((ay[0] + dy + 1) * 152 + ax[0] + dx + 1) * 64) + dqb;
    apix[1] = (u32)(((ay[1] + dy + 1) * 152 + ax[1] + dx + 1) * 64) + dqb;
  };

  auto stage = [&](int seg, int chunk) {
    const u64 ach = (u64)chunk * CHSZ;
    #pragma unroll
    for (int s = 0; s < 3; ++s) {
      const char* as = (const char*)Ap + (u64)s * ASPLIT + ach;
      GLL(as + apix[0], lds + s * 8192 + w * 1024);
      GLL(as + apix[1], lds + s * 8192 + (w + 4) * 1024);
    }
    const u64 bch = bbase + (u64)(seg * 32 + chunk) * 8192;
    #pragma unroll
    for (int s = 0; s < 3; ++s) {
      const char* bs = (const char*)Bp + (u64)s * BSPLIT + bch;
      GLL(bs + brow0, lds + 24576 + s * 8192 + w * 1024);
      GLL(bs + brow1, lds + 24576 + s * 8192 + (w + 4) * 1024);
    }
  };

  short8 Af[3][4], Bf[3][4];
  auto readFrags = [&]() {
    #pragma unroll
    for (int s = 0; s < 3; ++s)
      #pragma unroll
      for (int i = 0; i < 4; ++i) {
        Af[s][i] = *(const short8*)(lds + aF + s * 8192 + i * 1024);
        Bf[s][i] = *(const short8*)(lds + bF + s * 8192 + i * 1024);
      }
  };

  f32x4 acc[4][4];
  #pragma unroll
  for (int i = 0; i < 4; ++i)
    #pragma unroll
    for (int j = 0; j < 4; ++j) acc[i][j] = (f32x4){0.f, 0.f, 0.f, 0.f};

  segSetup(0);
  stage(0, 0);
  __syncthreads();
  readFrags();

  for (int it = 0; it < 288; ++it) {          // it = seg*32 + chunk
    const int nit = it + 1;
    const bool more = nit < 288;
    if (more && (nit & 31) == 0) segSetup(nit >> 5);
    __syncthreads();                          // all waves hold frags in regs
    if (more) stage(nit >> 5, nit & 31);      // overwrite LDS; drain overlapped
    #pragma unroll
    for (int i = 0; i < 4; ++i)
      #pragma unroll
      for (int j = 0; j < 4; ++j) {
        f32x4 c = acc[i][j];
        c = mfma16(Af[0][i], Bf[0][j], c);
        c = mfma16(Af[0][i], Bf[1][j], c);
        c = mfma16(Af[1][i], Bf[0][j], c);
        c = mfma16(Af[1][i], Bf[1][j], c);
        c = mfma16(Af[0][i], Bf[2][j], c);
        c = mfma16(Af[2][i], Bf[0][j], c);
        acc[i][j] = c;
      }
    __syncthreads();                          // staged chunk landed
    if (more) readFrags();
  }

  // epilogue: bias + relu + store (C/D: row=(lane>>4)*4+reg, col=lane&15)
  #pragma unroll
  for (int i = 0; i < 4; ++i) {
    const int mb = bm + wm + i * 16 + ((L >> 4) << 2);
    #pragma unroll
    for (int ri = 0; ri < 4; ++ri) {
      const int m = mb + ri;
      if (m < NPIX) {
        float* op = rpn + (size_t)m * CMID;
        #pragma unroll
        for (int j = 0; j < 4; ++j) {
          const int n = bn + wn + j * 16 + (L & 15);
          op[n] = fmaxf(acc[i][j][ri] + br[n], 0.f);
        }
      }
    }
  }
}

// ---------------------------------------------------------------------------
// Pack head weights: Wp[512][64] (cls 0-17, bbox 18-53, pad), bp[64].
// ---------------------------------------------------------------------------
__global__ __launch_bounds__(256) void k_packW(
    const float* __restrict__ Ws, const float* __restrict__ bs,
    const float* __restrict__ Wb, const float* __restrict__ bb,
    float* __restrict__ Wp, float* __restrict__ bp)
{
  int tt = blockIdx.x * 256 + threadIdx.x;
  int k = tt >> 6, o = tt & 63;
  float v = (o < 18) ? Ws[k * 18 + o] : ((o < 54) ? Wb[k * 36 + (o - 18)] : 0.f);
  Wp[tt] = v;
  if (tt < 64) bp[tt] = (tt < 18) ? bs[tt] : ((tt < 54) ? bb[tt - 18] : 0.f);
}

// ---------------------------------------------------------------------------
// Head GEMM: vals[M=15000][64] = rpn[M][512] * Wp[512][64] + bp.
// ---------------------------------------------------------------------------
__global__ __launch_bounds__(256) void k_headgemm(
    const float* __restrict__ rpn, const float* __restrict__ Wp,
    const float* __restrict__ bp, float* __restrict__ vals)
{
  __shared__ float As[32][132];
  __shared__ float Bs[32][64];
  const int tid = threadIdx.x;
  const int bm = blockIdx.x * 128;
  const int mt = tid >> 3;
  const int nt = tid & 7;
  const int kg = tid & 7;
  const int ar = tid >> 3;
  const int n4 = (tid & 15) * 4;
  const int kr = tid >> 4;
  const float4 z4 = make_float4(0.f, 0.f, 0.f, 0.f);

  float acc[4][8];
  #pragma unroll
  for (int i = 0; i < 4; ++i)
    #pragma unroll
    for (int j = 0; j < 8; ++j) acc[i][j] = 0.f;

  for (int kc = 0; kc < 512; kc += 32) {
    __syncthreads();
    #pragma unroll
    for (int rr = 0; rr < 128; rr += 32) {
      int m = bm + ar + rr;
      float4 v = (m < NPIX) ? *(const float4*)&rpn[(size_t)m * CMID + kc + kg * 4] : z4;
      As[kg * 4 + 0][ar + rr] = v.x; As[kg * 4 + 1][ar + rr] = v.y;
      As[kg * 4 + 2][ar + rr] = v.z; As[kg * 4 + 3][ar + rr] = v.w;
    }
    *(float4*)&Bs[kr][n4]      = *(const float4*)&Wp[(kc + kr) * 64 + n4];
    *(float4*)&Bs[kr + 16][n4] = *(const float4*)&Wp[(kc + kr + 16) * 64 + n4];
    __syncthreads();
    #pragma unroll
    for (int kk = 0; kk < 32; ++kk) {
      float4 a = *(const float4*)&As[kk][mt * 4];
      float4 b0 = *(const float4*)&Bs[kk][nt * 8];
      float4 b1 = *(const float4*)&Bs[kk][nt * 8 + 4];
      float av[4] = {a.x, a.y, a.z, a.w};
      float bv[8] = {b0.x, b0.y, b0.z, b0.w, b1.x, b1.y, b1.z, b1.w};
      #pragma unroll
      for (int i = 0; i < 4; ++i)
        #pragma unroll
        for (int j = 0; j < 8; ++j) acc[i][j] = fmaf(av[i], bv[j], acc[i][j]);
    }
  }
  float bias[8];
  #pragma unroll
  for (int j = 0; j < 8; ++j) bias[j] = bp[nt * 8 + j];
  #pragma unroll
  for (int rI = 0; rI < 4; ++rI) {
    int m = bm + mt * 4 + rI;
    if (m < NPIX) {
      float o[8];
      #pragma unroll
      for (int j = 0; j < 8; ++j) o[j] = acc[rI][j] + bias[j];
      float* op = vals + (size_t)m * 64 + nt * 8;
      *(float4*)op = *(float4*)&o[0];
      *(float4*)(op + 4) = *(float4*)&o[4];
    }
  }
}

// ---------------------------------------------------------------------------
// Decode: softmax + anchor decode + clip + min-size filter. 1 thread/anchor.
// ---------------------------------------------------------------------------
__global__ __launch_bounds__(256) void k_decode(
    const float* __restrict__ vals, const int* __restrict__ img,
    float* __restrict__ fg, float4* __restrict__ boxes)
{
  int gi = blockIdx.x * 256 + threadIdx.x;
  if (gi >= NANCH) return;
  const int p = gi / 9, a = gi - p * 9;
  const float AW[9] = {184.f, 368.f, 736.f, 128.f, 256.f, 512.f,  88.f, 176.f, 352.f};
  const float AH[9] = { 96.f, 192.f, 384.f, 128.f, 256.f, 512.f, 176.f, 352.f, 704.f};
  const int y = p / W_FM, x = p - y * W_FM;
  const float* row = vals + (size_t)p * 64;

  float c0 = row[2 * a], c1 = row[2 * a + 1];
  float score = 1.f / (1.f + expf(c0 - c1));

  float dxv = row[18 + 4 * a + 0];
  float dyv = row[18 + 4 * a + 1];
  float dwv = row[18 + 4 * a + 2];
  float dhv = row[18 + 4 * a + 3];

  float aw = AW[a], ah = AH[a];
  float acx = (float)(x * 16 + 8);
  float acy = (float)(y * 16 + 8);
  float pcx = dxv * aw + acx;
  float pcy = dyv * ah + acy;
  float pw = expf(dwv) * aw;
  float ph = expf(dhv) * ah;

  float imh1 = (float)img[0] - 1.f;
  float imw1 = (float)img[1] - 1.f;
  float b0 = fminf(fmaxf(pcx - 0.5f * pw, 0.f), imw1);
  float b1 = fminf(fmaxf(pcy - 0.5f * ph, 0.f), imh1);
  float b2 = fminf(fmaxf(pcx + 0.5f * pw, 0.f), imw1);
  float b3 = fminf(fmaxf(pcy + 0.5f * ph, 0.f), imh1);

  float bw = b2 - b0 + 1.f, bh = b3 - b1 + 1.f;
  if (!(bw >= 16.f && bh >= 16.f)) score = -1e9f;

  fg[gi] = score;
  boxes[gi] = make_float4(b0, b1, b2, b3);
}

// ---------------------------------------------------------------------------
// Radix-select (exact top-6000 threshold) machinery.
// ctl[0]=prefix/threshold, ctl[1]=kneed, ctl[2]=cntA, ctl[3]=cntB
// ---------------------------------------------------------------------------
__global__ void k_init(u32* __restrict__ hist, u32* __restrict__ ctl) {
  hist[threadIdx.x] = 0;
  if (threadIdx.x == 0) { ctl[0] = 0; ctl[1] = PRE_NMS_N; ctl[2] = 0; ctl[3] = 0; }
}

__global__ __launch_bounds__(256) void k_hist(
    const float* __restrict__ fg, u32* __restrict__ hist,
    const u32* __restrict__ ctl, int pass)
{
  __shared__ u32 h[256];
  h[threadIdx.x] = 0;
  __syncthreads();
  const int shift = 24 - 8 * pass;
  const u32 prefix = ctl[0];
  for (int i = blockIdx.x * 256 + threadIdx.x; i < NANCH; i += 128 * 256) {
    u32 key = fkey(fg[i]);
    bool match = (pass == 0) || ((key >> (shift + 8)) == prefix);
    if (match) atomicAdd(&h[(key >> shift) & 255], 1u);
  }
  __syncthreads();
  u32 c = h[threadIdx.x];
  if (c) atomicAdd(&hist[threadIdx.x], c);
}

__global__ void k_scan(u32* __restrict__ hist, u32* __restrict__ ctl) {
  if (threadIdx.x == 0) {
    u32 kneed = ctl[1];
    u32 cum = 0;
    int d = 0;
    for (int dd = 255; dd >= 0; --dd) {
      u32 c = hist[dd];
      if (cum + c >= kneed) { d = dd; break; }
      cum += c;
    }
    ctl[0] = (ctl[0] << 8) | (u32)d;
    ctl[1] = kneed - cum;
  }
  __syncthreads();
  hist[threadIdx.x] = 0;
}

__global__ __launch_bounds__(256) void k_compact(
    const float* __restrict__ fg, u32* __restrict__ ctl,
    u64* __restrict__ listA, u32* __restrict__ listB)
{
  int i = blockIdx.x * 256 + threadIdx.x;
  if (i >= NANCH) return;
  u32 T = ctl[0];
  u32 key = fkey(fg[i]);
  if (key > T) {
    u32 slot = atomicAdd(&ctl[2], 1u);
    listA[slot] = ((u64)key << 32) | (u64)(0xFFFFFFFFu - (u32)i);
  } else if (key == T) {
    u32 slot = atomicAdd(&ctl[3], 1u);
    if (slot < 8192) listB[slot] = (u32)i;
  }
}

__global__ __launch_bounds__(256) void k_tiefix(
    u32* __restrict__ ctl, const u32* __restrict__ listB, u64* __restrict__ listA)
{
  __shared__ u32 s[8192];
  const int tid = threadIdx.x;
  const u32 kneed = ctl[1];
  const u32 base = ctl[2];
  const u32 cntB = min(ctl[3], 8192u);
  const u32 T = ctl[0];
  if (kneed == 0) return;
  if (cntB == kneed) {
    for (u32 t = tid; t < kneed; t += 256)
      listA[base + t] = ((u64)T << 32) | (u64)(0xFFFFFFFFu - listB[t]);
    return;
  }
  u32 n2 = 1;
  while (n2 < cntB) n2 <<= 1;
  for (u32 i = tid; i < n2; i += 256) s[i] = (i < cntB) ? listB[i] : 0xFFFFFFFFu;
  __syncthreads();
  for (u32 k = 2; k <= n2; k <<= 1) {
    for (u32 j = k >> 1; j > 0; j >>= 1) {
      for (u32 i = tid; i < n2; i += 256) {
        u32 ixj = i ^ j;
        if (ixj > i) {
          u32 a = s[i], b = s[ixj];
          bool up = ((i & k) == 0);
          if ((a > b) == up) { s[i] = b; s[ixj] = a; }
        }
      }
      __syncthreads();
    }
  }
  for (u32 t = tid; t < kneed; t += 256)
    listA[base + t] = ((u64)T << 32) | (u64)(0xFFFFFFFFu - s[t]);
}

__global__ __launch_bounds__(1024) void k_sort(
    const u64* __restrict__ listA, u64* __restrict__ sorted)
{
  __shared__ u64 s[8192];
  const int tid = threadIdx.x;
  for (int i = tid; i < 8192; i += 1024) s[i] = (i < PRE_NMS_N) ? listA[i] : 0ull;
  __syncthreads();
  for (int k = 2; k <= 8192; k <<= 1) {
    for (int j = k >> 1; j > 0; j >>= 1) {
      for (int i = tid; i < 8192; i += 1024) {
        int ixj = i ^ j;
        if (ixj > i) {
          u64 a = s[i], b = s[ixj];
          bool up = ((i & k) == 0);
          if ((a < b) == up) { s[i] = b; s[ixj] = a; }
        }
      }
      __syncthreads();
    }
  }
  for (int i = tid; i < 8192; i += 1024) sorted[i] = s[i];
}

__global__ __launch_bounds__(256) void k_gather(
    const u64* __restrict__ sorted, const float4* __restrict__ boxes,
    float4* __restrict__ tb)
{
  int t = blockIdx.x * 256 + threadIdx.x;
  if (t >= PRE_NMS_N) return;
  u64 p = sorted[t];
  u32 idx = 0xFFFFFFFFu - (u32)(p & 0xFFFFFFFFull);
  tb[t] = boxes[idx];
}

// ---------------------------------------------------------------------------
// Suppression bitmask: mask[i][w] bit b == (IoU(i, w*64+b) > 0.7 && j > i)
// ---------------------------------------------------------------------------
__global__ __launch_bounds__(64) void k_mask(
    const float4* __restrict__ tb, u64* __restrict__ mask)
{
  __shared__ float4 cb[64];
  const int bj = blockIdx.x, bi = blockIdx.y, t = threadIdx.x;
  const int j0 = bj * 64;
  const int jn = min(64, PRE_NMS_N - j0);
  if (t < jn) cb[t] = tb[j0 + t];
  __syncthreads();
  const int i = bi * 64 + t;
  if (i >= PRE_NMS_N) return;
  const float4 b = tb[i];
  const float ai = (b.z - b.x + 1.f) * (b.w - b.y + 1.f);
  u64 bits = 0;
  for (int tt = 0; tt < jn; ++tt) {
    int j = j0 + tt;
    if (j <= i) continue;
    float4 c = cb[tt];
    float iw = fminf(b.z, c.z) - fmaxf(b.x, c.x) + 1.f;
    float ih = fminf(b.w, c.w) - fmaxf(b.y, c.y) + 1.f;
    float inter = fmaxf(iw, 0.f) * fmaxf(ih, 0.f);
    float aj = (c.z - c.x + 1.f) * (c.w - c.y + 1.f);
    float iou = inter / (ai + aj - inter);
    if (iou > 0.7f) bits |= (1ull << tt);
  }
  mask[(size_t)i * WPR + bj] = bits;
}

// ---------------------------------------------------------------------------
// Single-wave greedy NMS walk with register-resident removed-bitmask;
// early exit after 300 kept.
// ---------------------------------------------------------------------------
__global__ __launch_bounds__(64) void k_nms(
    const u64* __restrict__ mask, const float* __restrict__ tb,
    const u64* __restrict__ sorted, float* __restrict__ out)
{
  const int lane = threadIdx.x;
  u64 r0 = 0, r1 = 0;
  int kept = 0;
  const u32 kcut = fkey(-1e8f);
  for (int i = 0; i < PRE_NMS_N; ++i) {
    const int w = i >> 6, b = i & 63;
    u64 v0 = shfl64(r0, w & 63);
    u64 v1 = shfl64(r1, w & 63);
    u64 word = (w < 64) ? v0 : v1;
    if (!((word >> b) & 1ull)) {
      u32 key = (u32)(sorted[i] >> 32);
      if (key <= kcut) break;
      if (lane < 4) out[kept * 4 + lane] = tb[i * 4 + lane];
      ++kept;
      if (kept >= POST_NMS_N) break;
      const u64* row = mask + (size_t)i * WPR;
      r0 |= row[lane];
      if (lane < WPR - 64) r1 |= row[64 + lane];
    }
  }
  for (int j = kept * 4 + lane; j < POST_NMS_N * 4; j += 64) out[j] = 0.f;
}

// ---------------------------------------------------------------------------
extern "C" void kernel_launch(void* const* d_in, const int* in_sizes, int n_in,
                              void* d_out, int out_size, void* d_ws, size_t ws_size,
                              hipStream_t stream) {
  const float* fm  = (const float*)d_in[0];
  const float* Wr  = (const float*)d_in[1];
  const float* br  = (const float*)d_in[2];
  const float* Wsc = (const float*)d_in[3];
  const float* bsc = (const float*)d_in[4];
  const float* Wbb = (const float*)d_in[5];
  const float* bbb = (const float*)d_in[6];
  const int*   img = (const int*)d_in[7];
  float* out = (float*)d_out;

  char* w = (char*)d_ws;
  size_t off = 0;
  auto alloc = [&](size_t bytes) {
    size_t p = off;
    off = (off + bytes + 255) & ~(size_t)255;
    return p;
  };
  float* rpn    = (float*)(w + alloc((size_t)NPIX * CMID * 4));       // 30.72 MB
  float* fg     = (float*)(w + alloc((size_t)NANCH * 4));
  float4* boxes = (float4*)(w + alloc((size_t)NANCH * 16));
  u32* hist     = (u32*)(w + alloc(1024));
  u32* ctl      = (u32*)(w + alloc(64));
  u64* listA    = (u64*)(w + alloc((size_t)PRE_NMS_N * 8));
  u32* listB    = (u32*)(w + alloc(8192 * 4));
  u64* sorted   = (u64*)(w + alloc(8192 * 8));
  float4* topbox= (float4*)(w + alloc((size_t)PRE_NMS_N * 16));
  u64* mask     = (u64*)(w + alloc((size_t)PRE_NMS_N * WPR * 8));     // 4.5 MB
  float* Wp     = (float*)(w + alloc(512 * 64 * 4));
  float* bp     = (float*)(w + alloc(64 * 4));
  float* vals   = (float*)(w + alloc((size_t)NPIX * 64 * 4));         // 3.84 MB
  unsigned short* Ap = (unsigned short*)(w + alloc((size_t)(3 * ASPLIT))); // 97.1 MB
  unsigned short* Bp = (unsigned short*)(w + alloc((size_t)(3 * BSPLIT))); // 28.3 MB

  // 1. precision-split + pack (A halo-zero, A pack, B pack, head-W pack)
  k_zeroA<<<dim3((3 * 32 * 808 + 255) / 256), dim3(256), 0, stream>>>(Ap);
  k_splitA<<<dim3(1024), dim3(256), 0, stream>>>(fm, Ap);
  k_splitB<<<dim3(144, 8), dim3(256), 0, stream>>>(Wr, Bp);
  k_packW<<<dim3(128), dim3(256), 0, stream>>>(Wsc, bsc, Wbb, bbb, Wp, bp);
  // 2. conv (3x3 + bias + relu), pipelined swizzled MFMA
  k_conv8<<<dim3(118 * 4), dim3(256), 0, stream>>>(Ap, Bp, br, rpn);
  // 3. heads + decode
  k_headgemm<<<dim3(118), dim3(256), 0, stream>>>(rpn, Wp, bp, vals);
  k_decode<<<dim3((NANCH + 255) / 256), dim3(256), 0, stream>>>(vals, img, fg, boxes);
  // 4. exact top-6000 radix select
  k_init<<<1, 256, 0, stream>>>(hist, ctl);
  for (int pass = 0; pass < 4; ++pass) {
    k_hist<<<128, 256, 0, stream>>>(fg, hist, ctl, pass);
    k_scan<<<1, 256, 0, stream>>>(hist, ctl);
  }
  k_compact<<<(NANCH + 255) / 256, 256, 0, stream>>>(fg, ctl, listA, listB);
  k_tiefix<<<1, 256, 0, stream>>>(ctl, listB, listA);
  // 5. sort (desc score, asc index) + gather
  k_sort<<<1, 1024, 0, stream>>>(listA, sorted);
  k_gather<<<(PRE_NMS_N + 255) / 256, 256, 0, stream>>>(sorted, boxes, topbox);
  // 6. NMS mask + single-wave walk + emit 300
  k_mask<<<dim3(WPR, WPR), 64, 0, stream>>>(topbox, mask);
  k_nms<<<1, 64, 0, stream>>>(mask, (const float*)topbox, sorted, out);
}

// Round 7
// 1176.472 us; speedup vs baseline: 1.6519x; 1.0526x over previous
//
#include <hip/hip_runtime.h>
#include <hip/hip_bf16.h>

typedef unsigned int u32;
typedef unsigned long long u64;

#define H_FM 100
#define W_FM 150
#define CIN 1024
#define CMID 512
#define NPIX 15000          // H_FM * W_FM
#define NANCH 135000        // NPIX * 9
#define PRE_NMS_N 6000
#define POST_NMS_N 300
#define WPR 94              // ceil(6000/64) words per mask row

// padded A-pack geometry: rows -1..102 (104), cols -1..150 (152)
#define PW 152
#define PH 104
#define PPIX (PW * PH)          // 15808 pixels
#define CHSZ ((u64)PPIX * 64)   // bytes per (chunk) plane = 1,011,712
#define ASPLIT (32 * CHSZ)      // per split = 32,374,784
#define BSPLIT ((u64)9216 * 512 * 2)  // 9,437,184 per split

typedef __attribute__((ext_vector_type(8))) short short8;
typedef __attribute__((ext_vector_type(8))) __bf16 bf16x8;
typedef __attribute__((ext_vector_type(4))) float f32x4;

__device__ __forceinline__ u32 fkey(float f) {
  u32 u = __float_as_uint(f);
  return (u & 0x80000000u) ? ~u : (u | 0x80000000u);
}

__device__ __forceinline__ u64 shfl64(u64 v, int src) {
  u32 lo = (u32)__shfl((int)(u32)v, src, 64);
  u32 hi = (u32)__shfl((int)(u32)(v >> 32), src, 64);
  return ((u64)hi << 32) | (u64)lo;
}

// MFMA wrapper: tolerate either short8 or bf16x8 builtin operand signature.
struct FragArg {
  short8 v;
  __device__ operator short8() const { return v; }
  __device__ operator bf16x8() const { return __builtin_bit_cast(bf16x8, v); }
};
__device__ __forceinline__ f32x4 mfma16(short8 a, short8 b, f32x4 c) {
  return __builtin_amdgcn_mfma_f32_16x16x32_bf16(FragArg{a}, FragArg{b}, c, 0, 0, 0);
}

#define GLL(gp, lp) __builtin_amdgcn_global_load_lds(                        \
    (const __attribute__((address_space(1))) unsigned int*)(gp),             \
    (__attribute__((address_space(3))) unsigned int*)(lp), 16, 0, 0)

__device__ __forceinline__ void split3(float f, unsigned short& a,
                                       unsigned short& b, unsigned short& c) {
  __hip_bfloat16 h0 = __float2bfloat16(f);
  float f0 = __bfloat162float(h0);
  float r1 = f - f0;
  __hip_bfloat16 h1 = __float2bfloat16(r1);
  float r2 = r1 - __bfloat162float(h1);
  __hip_bfloat16 h2 = __float2bfloat16(r2);
  a = *(unsigned short*)&h0;
  b = *(unsigned short*)&h1;
  c = *(unsigned short*)&h2;
}

// ---------------------------------------------------------------------------
// Split fm into 3 bf16 planes packed [split][chunk32][padded pixel][64 B],
// with halo zeroing fused in (disjoint writes, no ordering needed).
// ---------------------------------------------------------------------------
__global__ __launch_bounds__(256) void k_splitA(
    const float* __restrict__ src, unsigned short* __restrict__ Ap)
{
  // fused halo zero: 3 splits x 32 chunks x 808 halo pixels
  {
    int z = blockIdx.x * 256 + threadIdx.x;
    if (z < 3 * 32 * 808) {
      int sc = z / 808, h = z - sc * 808;
      int s = sc >> 5, c = sc & 31;
      int pp;
      if (h < 152) pp = h;                                    // row 0
      else if (h < 608) pp = 101 * 152 + (h - 152);           // rows 101..103
      else { int k = h - 608; pp = ((k >> 1) + 1) * 152 + ((k & 1) ? 151 : 0); }
      float4* dst = (float4*)((char*)Ap + (u64)s * ASPLIT + (u64)c * CHSZ + (u64)pp * 64);
      float4 zz = make_float4(0.f, 0.f, 0.f, 0.f);
      dst[0] = zz; dst[1] = zz; dst[2] = zz; dst[3] = zz;
    }
  }
  const int ntot = NPIX * 256;      // (pixel, group-of-4-ch)
  for (int id = blockIdx.x * 256 + threadIdx.x; id < ntot; id += gridDim.x * 256) {
    int p = id >> 8, g = id & 255;
    float4 v = *(const float4*)(src + (size_t)p * 1024 + g * 4);
    float f[4] = {v.x, v.y, v.z, v.w};
    ushort4 o0, o1, o2;
    unsigned short* q0 = (unsigned short*)&o0;
    unsigned short* q1 = (unsigned short*)&o1;
    unsigned short* q2 = (unsigned short*)&o2;
    #pragma unroll
    for (int e = 0; e < 4; ++e) split3(f[e], q0[e], q1[e], q2[e]);
    int yy = p / 150;
    int pp = (yy + 1) * 152 + (p - yy * 150) + 1;
    u64 off = (u64)(g >> 3) * CHSZ + (u64)pp * 64 + (g & 7) * 8;
    *(ushort4*)((char*)Ap + off) = o0;
    *(ushort4*)((char*)Ap + ASPLIT + off) = o1;
    *(ushort4*)((char*)Ap + 2 * ASPLIT + off) = o2;
  }
}

// ---------------------------------------------------------------------------
// Split + transpose + pack weights: W [9216 k][512 n] fp32 ->
// 3 bf16 planes [nblk 4][seg 9][chunk 32][row 128][64 B].
// ---------------------------------------------------------------------------
__global__ __launch_bounds__(256) void k_splitB(
    const float* __restrict__ Wsrc, unsigned short* __restrict__ Bp)
{
  __shared__ float tile[64][65];
  const int k0 = blockIdx.x * 64;   // 144 blocks
  const int n0 = blockIdx.y * 64;   // 8 blocks
  const int tid = threadIdx.x;
  const int lr = tid >> 4;
  const int lc = (tid & 15) * 4;
  #pragma unroll
  for (int rr = 0; rr < 64; rr += 16) {
    float4 v = *(const float4*)&Wsrc[(size_t)(k0 + lr + rr) * CMID + n0 + lc];
    tile[lr + rr][lc + 0] = v.x; tile[lr + rr][lc + 1] = v.y;
    tile[lr + rr][lc + 2] = v.z; tile[lr + rr][lc + 3] = v.w;
  }
  __syncthreads();
  const int n = n0 + (tid >> 2);
  const int kk = k0 + (tid & 3) * 16;
  unsigned short b0[16], b1[16], b2[16];
  #pragma unroll
  for (int e = 0; e < 16; ++e)
    split3(tile[(tid & 3) * 16 + e][tid >> 2], b0[e], b1[e], b2[e]);
  const int nblk = n >> 7, row = n & 127;
  const int seg = kk >> 10, chunk = (kk >> 5) & 31, ch = kk & 31;
  u64 base = ((u64)((nblk * 9 + seg) * 32 + chunk)) * 8192 + row * 64 + ch * 2;
  #pragma unroll
  for (int q = 0; q < 4; ++q) {
    *(ushort4*)((char*)Bp + base + q * 8) = *(ushort4*)&b0[q * 4];
    *(ushort4*)((char*)Bp + BSPLIT + base + q * 8) = *(ushort4*)&b1[q * 4];
    *(ushort4*)((char*)Bp + 2 * BSPLIT + base + q * 8) = *(ushort4*)&b2[q * 4];
  }
}

// ---------------------------------------------------------------------------
// k_conv8: 128x128 tile, 472 blocks, BK=32, bf16x3 (6 products).
// XOR-swizzled LDS (conflict-free), register frag pre-read, single-buffer
// stage(next)->compute->drain pipeline, dense ~1KB GLL sources.
// ---------------------------------------------------------------------------
__global__ __launch_bounds__(256, 2) void k_conv8(
    const unsigned short* __restrict__ Ap, const unsigned short* __restrict__ Bp,
    const float* __restrict__ br, float* __restrict__ rpn)
{
  __shared__ char lds[49152];
  const int tid = threadIdx.x;
  const int L = tid & 63;
  const int w = tid >> 6;
  const int nblk = blockIdx.x & 3;
  const int bn = nblk * 128;
  const int bm = (blockIdx.x >> 2) * 128;
  const int wm = (w >> 1) * 64, wn = (w & 1) * 64;

  const int r = L >> 2;
  const u32 dqb = (u32)(((L & 3) ^ ((r >> 1) & 3)) * 16);

  int ay[2], ax[2];
  {
    int m0 = bm + w * 16 + r;       ay[0] = m0 / 150; ax[0] = m0 - ay[0] * 150;
    int m1 = bm + (w + 4) * 16 + r; ay[1] = m1 / 150; ax[1] = m1 - ay[1] * 150;
  }
  const u32 brow0 = (u32)((w * 16 + r) * 64) + dqb;
  const u32 brow1 = (u32)(((w + 4) * 16 + r) * 64) + dqb;
  const u64 bbase = (u64)nblk * 9 * 32 * 8192;

  const int fr = L & 15, fq = L >> 4;
  const u32 fsw = (u32)((fq ^ ((fr >> 1) & 3)) * 16);
  const u32 aF = (u32)((wm >> 4) * 1024 + fr * 64) + fsw;
  const u32 bF = 24576u + (u32)((wn >> 4) * 1024 + fr * 64) + fsw;

  u32 apix[2];
  auto segSetup = [&](int seg) {
    int dy = seg / 3 - 1, dx = seg - (seg / 3) * 3 - 1;
    apix[0] = (u32)(((ay[0] + dy + 1) * 152 + ax[0] + dx + 1) * 64) + dqb;
    apix[1] = (u32)(((ay[1] + dy + 1) * 152 + ax[1] + dx + 1) * 64) + dqb;
  };

  auto stage = [&](int seg, int chunk) {
    const u64 ach = (u64)chunk * CHSZ;
    #pragma unroll
    for (int s = 0; s < 3; ++s) {
      const char* as = (const char*)Ap + (u64)s * ASPLIT + ach;
      GLL(as + apix[0], lds + s * 8192 + w * 1024);
      GLL(as + apix[1], lds + s * 8192 + (w + 4) * 1024);
    }
    const u64 bch = bbase + (u64)(seg * 32 + chunk) * 8192;
    #pragma unroll
    for (int s = 0; s < 3; ++s) {
      const char* bs = (const char*)Bp + (u64)s * BSPLIT + bch;
      GLL(bs + brow0, lds + 24576 + s * 8192 + w * 1024);
      GLL(bs + brow1, lds + 24576 + s * 8192 + (w + 4) * 1024);
    }
  };

  short8 Af[3][4], Bf[3][4];
  auto readFrags = [&]() {
    #pragma unroll
    for (int s = 0; s < 3; ++s)
      #pragma unroll
      for (int i = 0; i < 4; ++i) {
        Af[s][i] = *(const short8*)(lds + aF + s * 8192 + i * 1024);
        Bf[s][i] = *(const short8*)(lds + bF + s * 8192 + i * 1024);
      }
  };

  f32x4 acc[4][4];
  #pragma unroll
  for (int i = 0; i < 4; ++i)
    #pragma unroll
    for (int j = 0; j < 4; ++j) acc[i][j] = (f32x4){0.f, 0.f, 0.f, 0.f};

  segSetup(0);
  stage(0, 0);
  __syncthreads();
  readFrags();

  for (int it = 0; it < 288; ++it) {          // it = seg*32 + chunk
    const int nit = it + 1;
    const bool more = nit < 288;
    if (more && (nit & 31) == 0) segSetup(nit >> 5);
    __syncthreads();                          // all waves hold frags in regs
    if (more) stage(nit >> 5, nit & 31);      // overwrite LDS; drain overlapped
    #pragma unroll
    for (int i = 0; i < 4; ++i)
      #pragma unroll
      for (int j = 0; j < 4; ++j) {
        f32x4 c = acc[i][j];
        c = mfma16(Af[0][i], Bf[0][j], c);
        c = mfma16(Af[0][i], Bf[1][j], c);
        c = mfma16(Af[1][i], Bf[0][j], c);
        c = mfma16(Af[1][i], Bf[1][j], c);
        c = mfma16(Af[0][i], Bf[2][j], c);
        c = mfma16(Af[2][i], Bf[0][j], c);
        acc[i][j] = c;
      }
    __syncthreads();                          // staged chunk landed
    if (more) readFrags();
  }

  #pragma unroll
  for (int i = 0; i < 4; ++i) {
    const int mb = bm + wm + i * 16 + ((L >> 4) << 2);
    #pragma unroll
    for (int ri = 0; ri < 4; ++ri) {
      const int m = mb + ri;
      if (m < NPIX) {
        float* op = rpn + (size_t)m * CMID;
        #pragma unroll
        for (int j = 0; j < 4; ++j) {
          const int n = bn + wn + j * 16 + (L & 15);
          op[n] = fmaxf(acc[i][j][ri] + br[n], 0.f);
        }
      }
    }
  }
}

// ---------------------------------------------------------------------------
// Pack head weights Wp[512][64] + bp[64]; fused: zero hist + ctl.
// ---------------------------------------------------------------------------
__global__ __launch_bounds__(256) void k_packW(
    const float* __restrict__ Ws, const float* __restrict__ bs,
    const float* __restrict__ Wb, const float* __restrict__ bb,
    float* __restrict__ Wp, float* __restrict__ bp,
    u32* __restrict__ hist, u32* __restrict__ ctl)
{
  int tt = blockIdx.x * 256 + threadIdx.x;
  int k = tt >> 6, o = tt & 63;
  float v = (o < 18) ? Ws[k * 18 + o] : ((o < 54) ? Wb[k * 36 + (o - 18)] : 0.f);
  Wp[tt] = v;
  if (tt < 64) bp[tt] = (tt < 18) ? bs[tt] : ((tt < 54) ? bb[tt - 18] : 0.f);
  if (tt < 256) hist[tt] = 0;
  if (tt < 16) ctl[tt] = 0;
  if (tt == 1) ctl[1] = PRE_NMS_N;   // kneed
}

// ---------------------------------------------------------------------------
// Head GEMM + fused decode: 472 blocks x 32 rows.
// vals row = rpn[m][512] * Wp[512][64] + bp ; then softmax/decode in-block.
// ---------------------------------------------------------------------------
__global__ __launch_bounds__(256) void k_headdec(
    const float* __restrict__ rpn, const float* __restrict__ Wp,
    const float* __restrict__ bp, const int* __restrict__ img,
    float* __restrict__ fg, float4* __restrict__ boxes)
{
  __shared__ float As[32][33];
  __shared__ float Bs[32][64];
  __shared__ float vs[32 * 64];
  const int tid = threadIdx.x;
  const int bm = blockIdx.x * 32;
  const int r  = tid >> 3;          // row 0..31 (load & compute)
  const int kg = tid & 7;           // A-load k-group
  const int c8 = (tid & 7) * 8;     // compute col base
  const int n4 = (tid & 15) * 4;    // B-load
  const int kr = tid >> 4;          // B-load row 0..15
  const float4 z4 = make_float4(0.f, 0.f, 0.f, 0.f);

  float acc[8];
  #pragma unroll
  for (int j = 0; j < 8; ++j) acc[j] = 0.f;

  for (int kc = 0; kc < 512; kc += 32) {
    __syncthreads();
    {
      int m = bm + r;
      float4 v = (m < NPIX) ? *(const float4*)&rpn[(size_t)m * CMID + kc + kg * 4] : z4;
      As[kg * 4 + 0][r] = v.x; As[kg * 4 + 1][r] = v.y;
      As[kg * 4 + 2][r] = v.z; As[kg * 4 + 3][r] = v.w;
    }
    *(float4*)&Bs[kr][n4]      = *(const float4*)&Wp[(kc + kr) * 64 + n4];
    *(float4*)&Bs[kr + 16][n4] = *(const float4*)&Wp[(kc + kr + 16) * 64 + n4];
    __syncthreads();
    #pragma unroll
    for (int kk = 0; kk < 32; ++kk) {
      float a = As[kk][r];
      float4 b0 = *(const float4*)&Bs[kk][c8];
      float4 b1 = *(const float4*)&Bs[kk][c8 + 4];
      acc[0] = fmaf(a, b0.x, acc[0]); acc[1] = fmaf(a, b0.y, acc[1]);
      acc[2] = fmaf(a, b0.z, acc[2]); acc[3] = fmaf(a, b0.w, acc[3]);
      acc[4] = fmaf(a, b1.x, acc[4]); acc[5] = fmaf(a, b1.y, acc[5]);
      acc[6] = fmaf(a, b1.z, acc[6]); acc[7] = fmaf(a, b1.w, acc[7]);
    }
  }
  __syncthreads();
  #pragma unroll
  for (int j = 0; j < 8; ++j) vs[r * 64 + c8 + j] = acc[j] + bp[c8 + j];
  __syncthreads();

  const float AW[9] = {184.f, 368.f, 736.f, 128.f, 256.f, 512.f,  88.f, 176.f, 352.f};
  const float AH[9] = { 96.f, 192.f, 384.f, 128.f, 256.f, 512.f, 176.f, 352.f, 704.f};
  const float imh1 = (float)img[0] - 1.f;
  const float imw1 = (float)img[1] - 1.f;
  for (int id = tid; id < 32 * 9; id += 256) {
    int pl = id / 9, a = id - pl * 9;
    int p = bm + pl;
    if (p >= NPIX) break;
    const float* row = vs + pl * 64;
    const int y = p / W_FM, x = p - y * W_FM;

    float c0 = row[2 * a], c1 = row[2 * a + 1];
    float score = 1.f / (1.f + expf(c0 - c1));

    float dxv = row[18 + 4 * a + 0];
    float dyv = row[18 + 4 * a + 1];
    float dwv = row[18 + 4 * a + 2];
    float dhv = row[18 + 4 * a + 3];

    float aw = AW[a], ah = AH[a];
    float acx = (float)(x * 16 + 8);
    float acy = (float)(y * 16 + 8);
    float pcx = dxv * aw + acx;
    float pcy = dyv * ah + acy;
    float pw = expf(dwv) * aw;
    float ph = expf(dhv) * ah;

    float b0 = fminf(fmaxf(pcx - 0.5f * pw, 0.f), imw1);
    float b1 = fminf(fmaxf(pcy - 0.5f * ph, 0.f), imh1);
    float b2 = fminf(fmaxf(pcx + 0.5f * pw, 0.f), imw1);
    float b3 = fminf(fmaxf(pcy + 0.5f * ph, 0.f), imh1);

    float bw = b2 - b0 + 1.f, bh = b3 - b1 + 1.f;
    if (!(bw >= 16.f && bh >= 16.f)) score = -1e9f;

    int gi = p * 9 + a;
    fg[gi] = score;
    boxes[gi] = make_float4(b0, b1, b2, b3);
  }
}

// ---------------------------------------------------------------------------
// Radix-select (exact top-6000 threshold).
// ctl[0]=prefix/threshold, ctl[1]=kneed, ctl[2]=cntA, ctl[3]=cntB, ctl[8]=nvalid
// ---------------------------------------------------------------------------
__global__ __launch_bounds__(256) void k_hist(
    const float* __restrict__ fg, u32* __restrict__ hist,
    const u32* __restrict__ ctl, int pass)
{
  __shared__ u32 h[256];
  h[threadIdx.x] = 0;
  __syncthreads();
  const int shift = 24 - 8 * pass;
  const u32 prefix = ctl[0];
  for (int i = blockIdx.x * 256 + threadIdx.x; i < NANCH; i += 128 * 256) {
    u32 key = fkey(fg[i]);
    bool match = (pass == 0) || ((key >> (shift + 8)) == prefix);
    if (match) atomicAdd(&h[(key >> shift) & 255], 1u);
  }
  __syncthreads();
  u32 c = h[threadIdx.x];
  if (c) atomicAdd(&hist[threadIdx.x], c);
}

__global__ void k_scan(u32* __restrict__ hist, u32* __restrict__ ctl) {
  if (threadIdx.x == 0) {
    u32 kneed = ctl[1];
    u32 cum = 0;
    int d = 0;
    for (int dd = 255; dd >= 0; --dd) {
      u32 c = hist[dd];
      if (cum + c >= kneed) { d = dd; break; }
      cum += c;
    }
    ctl[0] = (ctl[0] << 8) | (u32)d;
    ctl[1] = kneed - cum;
  }
  __syncthreads();
  hist[threadIdx.x] = 0;
}

__global__ __launch_bounds__(256) void k_compact(
    const float* __restrict__ fg, u32* __restrict__ ctl,
    u64* __restrict__ listA, u32* __restrict__ listB)
{
  int i = blockIdx.x * 256 + threadIdx.x;
  if (i >= NANCH) return;
  u32 T = ctl[0];
  u32 key = fkey(fg[i]);
  if (key > T) {
    u32 slot = atomicAdd(&ctl[2], 1u);
    listA[slot] = ((u64)key << 32) | (u64)(0xFFFFFFFFu - (u32)i);
  } else if (key == T) {
    u32 slot = atomicAdd(&ctl[3], 1u);
    if (slot < 8192) listB[slot] = (u32)i;
  }
}

__global__ __launch_bounds__(256) void k_tiefix(
    u32* __restrict__ ctl, const u32* __restrict__ listB, u64* __restrict__ listA)
{
  __shared__ u32 s[8192];
  const int tid = threadIdx.x;
  const u32 kneed = ctl[1];
  const u32 base = ctl[2];
  const u32 cntB = min(ctl[3], 8192u);
  const u32 T = ctl[0];
  if (kneed == 0) return;
  if (cntB == kneed) {
    for (u32 t = tid; t < kneed; t += 256)
      listA[base + t] = ((u64)T << 32) | (u64)(0xFFFFFFFFu - listB[t]);
    return;
  }
  u32 n2 = 1;
  while (n2 < cntB) n2 <<= 1;
  for (u32 i = tid; i < n2; i += 256) s[i] = (i < cntB) ? listB[i] : 0xFFFFFFFFu;
  __syncthreads();
  for (u32 k = 2; k <= n2; k <<= 1) {
    for (u32 j = k >> 1; j > 0; j >>= 1) {
      for (u32 i = tid; i < n2; i += 256) {
        u32 ixj = i ^ j;
        if (ixj > i) {
          u32 a = s[i], b = s[ixj];
          bool up = ((i & k) == 0);
          if ((a > b) == up) { s[i] = b; s[ixj] = a; }
        }
      }
      __syncthreads();
    }
  }
  for (u32 t = tid; t < kneed; t += 256)
    listA[base + t] = ((u64)T << 32) | (u64)(0xFFFFFFFFu - s[t]);
}

__global__ __launch_bounds__(1024) void k_sort(
    const u64* __restrict__ listA, u64* __restrict__ sorted)
{
  __shared__ u64 s[8192];
  const int tid = threadIdx.x;
  for (int i = tid; i < 8192; i += 1024) s[i] = (i < PRE_NMS_N) ? listA[i] : 0ull;
  __syncthreads();
  for (int k = 2; k <= 8192; k <<= 1) {
    for (int j = k >> 1; j > 0; j >>= 1) {
      for (int i = tid; i < 8192; i += 1024) {
        int ixj = i ^ j;
        if (ixj > i) {
          u64 a = s[i], b = s[ixj];
          bool up = ((i & k) == 0);
          if ((a < b) == up) { s[i] = b; s[ixj] = a; }
        }
      }
      __syncthreads();
    }
  }
  for (int i = tid; i < 8192; i += 1024) sorted[i] = s[i];
}

// gather top boxes; fused: count valid (score > -1e8) into ctl[8]
__global__ __launch_bounds__(256) void k_gather(
    const u64* __restrict__ sorted, const float4* __restrict__ boxes,
    float4* __restrict__ tb, u32* __restrict__ ctl)
{
  int t = blockIdx.x * 256 + threadIdx.x;
  const u32 kcut = fkey(-1e8f);
  bool inb = t < PRE_NMS_N;
  u64 p = inb ? sorted[t] : 0ull;
  bool valid = inb && ((u32)(p >> 32) > kcut);
  u64 ball = __ballot(valid);
  if ((threadIdx.x & 63) == 0 && ball) atomicAdd(&ctl[8], (u32)__popcll(ball));
  if (!inb) return;
  u32 idx = 0xFFFFFFFFu - (u32)(p & 0xFFFFFFFFull);
  tb[t] = boxes[idx];
}

// ---------------------------------------------------------------------------
// Suppression bitmask: mask[i][w] bit b == (IoU(i, w*64+b) > 0.7 && j > i)
// ---------------------------------------------------------------------------
__global__ __launch_bounds__(64) void k_mask(
    const float4* __restrict__ tb, u64* __restrict__ mask)
{
  __shared__ float4 cb[64];
  const int bj = blockIdx.x, bi = blockIdx.y, t = threadIdx.x;
  const int j0 = bj * 64;
  const int jn = min(64, PRE_NMS_N - j0);
  if (t < jn) cb[t] = tb[j0 + t];
  __syncthreads();
  const int i = bi * 64 + t;
  if (i >= PRE_NMS_N) return;
  const float4 b = tb[i];
  const float ai = (b.z - b.x + 1.f) * (b.w - b.y + 1.f);
  u64 bits = 0;
  for (int tt = 0; tt < jn; ++tt) {
    int j = j0 + tt;
    if (j <= i) continue;
    float4 c = cb[tt];
    float iw = fminf(b.z, c.z) - fmaxf(b.x, c.x) + 1.f;
    float ih = fminf(b.w, c.w) - fmaxf(b.y, c.y) + 1.f;
    float inter = fmaxf(iw, 0.f) * fmaxf(ih, 0.f);
    float aj = (c.z - c.x + 1.f) * (c.w - c.y + 1.f);
    float iou = inter / (ai + aj - inter);
    if (iou > 0.7f) bits |= (1ull << tt);
  }
  mask[(size_t)i * WPR + bj] = bits;
}

// ---------------------------------------------------------------------------
// Single-wave greedy NMS walk, word-level ffs scanning over live bits.
// removed-bitmask in registers (lane -> words lane, lane+64). Early exit @300.
// ---------------------------------------------------------------------------
__global__ __launch_bounds__(64) void k_nms(
    const u64* __restrict__ mask, const float* __restrict__ tb,
    const u32* __restrict__ ctl, float* __restrict__ out)
{
  const int lane = threadIdx.x;
  const int nvalid = min((int)ctl[8], PRE_NMS_N);
  u64 r0 = 0, r1 = 0;
  int kept = 0;
  for (int w = 0; w < WPR && kept < POST_NMS_N; ++w) {
    const int base = w << 6;
    if (base >= nvalid) break;
    u64 rw = (w < 64) ? shfl64(r0, w) : shfl64(r1, w - 64);
    u64 live = ~rw;
    if (base + 64 > nvalid) live &= ((1ull << (nvalid - base)) - 1ull);
    while (live) {
      int b = (int)(__ffsll((long long)live) - 1);
      int i = base + b;
      if (lane < 4) out[kept * 4 + lane] = tb[i * 4 + lane];
      ++kept;
      if (kept >= POST_NMS_N) break;
      const u64* row = mask + (size_t)i * WPR;
      u64 m0 = row[lane];
      u64 m1 = (lane < WPR - 64) ? row[64 + lane] : 0ull;
      r0 |= m0; r1 |= m1;
      u64 rwi = (w < 64) ? shfl64(m0, w) : shfl64(m1, w - 64);
      live &= ~rwi;
      live = (b == 63) ? 0ull : (live & (~0ull << (b + 1)));
    }
  }
  for (int j = kept * 4 + lane; j < POST_NMS_N * 4; j += 64) out[j] = 0.f;
}

// ---------------------------------------------------------------------------
extern "C" void kernel_launch(void* const* d_in, const int* in_sizes, int n_in,
                              void* d_out, int out_size, void* d_ws, size_t ws_size,
                              hipStream_t stream) {
  const float* fm  = (const float*)d_in[0];
  const float* Wr  = (const float*)d_in[1];
  const float* br  = (const float*)d_in[2];
  const float* Wsc = (const float*)d_in[3];
  const float* bsc = (const float*)d_in[4];
  const float* Wbb = (const float*)d_in[5];
  const float* bbb = (const float*)d_in[6];
  const int*   img = (const int*)d_in[7];
  float* out = (float*)d_out;

  char* w = (char*)d_ws;
  size_t off = 0;
  auto alloc = [&](size_t bytes) {
    size_t p = off;
    off = (off + bytes + 255) & ~(size_t)255;
    return p;
  };
  float* rpn    = (float*)(w + alloc((size_t)NPIX * CMID * 4));       // 30.72 MB
  float* fg     = (float*)(w + alloc((size_t)NANCH * 4));
  float4* boxes = (float4*)(w + alloc((size_t)NANCH * 16));
  u32* hist     = (u32*)(w + alloc(1024));
  u32* ctl      = (u32*)(w + alloc(64));
  u64* listA    = (u64*)(w + alloc((size_t)PRE_NMS_N * 8));
  u32* listB    = (u32*)(w + alloc(8192 * 4));
  u64* sorted   = (u64*)(w + alloc(8192 * 8));
  float4* topbox= (float4*)(w + alloc((size_t)PRE_NMS_N * 16));
  u64* mask     = (u64*)(w + alloc((size_t)PRE_NMS_N * WPR * 8));     // 4.5 MB
  float* Wp     = (float*)(w + alloc(512 * 64 * 4));
  float* bp     = (float*)(w + alloc(64 * 4));
  unsigned short* Ap = (unsigned short*)(w + alloc((size_t)(3 * ASPLIT))); // 97.1 MB
  unsigned short* Bp = (unsigned short*)(w + alloc((size_t)(3 * BSPLIT))); // 28.3 MB

  // 1. precision-split + pack (halo-zero fused in splitA; hist/ctl init in packW)
  k_splitA<<<dim3(1024), dim3(256), 0, stream>>>(fm, Ap);
  k_splitB<<<dim3(144, 8), dim3(256), 0, stream>>>(Wr, Bp);
  k_packW<<<dim3(128), dim3(256), 0, stream>>>(Wsc, bsc, Wbb, bbb, Wp, bp, hist, ctl);
  // 2. conv (3x3 + bias + relu), pipelined swizzled MFMA
  k_conv8<<<dim3(118 * 4), dim3(256), 0, stream>>>(Ap, Bp, br, rpn);
  // 3. heads + fused decode
  k_headdec<<<dim3(472), dim3(256), 0, stream>>>(rpn, Wp, bp, img, fg, boxes);
  // 4. exact top-6000 radix select
  for (int pass = 0; pass < 4; ++pass) {
    k_hist<<<128, 256, 0, stream>>>(fg, hist, ctl, pass);
    k_scan<<<1, 256, 0, stream>>>(hist, ctl);
  }
  k_compact<<<(NANCH + 255) / 256, 256, 0, stream>>>(fg, ctl, listA, listB);
  k_tiefix<<<1, 256, 0, stream>>>(ctl, listB, listA);
  // 5. sort (desc score, asc index) + gather (+ valid count)
  k_sort<<<1, 1024, 0, stream>>>(listA, sorted);
  k_gather<<<(PRE_NMS_N + 255) / 256, 256, 0, stream>>>(sorted, boxes, topbox, ctl);
  // 6. NMS mask + single-wave ffs walk + emit 300
  k_mask<<<dim3(WPR, WPR), 64, 0, stream>>>(topbox, mask);
  k_nms<<<1, 64, 0, stream>>>(mask, (const float*)topbox, ctl, out);
}